// Round 1
// baseline (446.160 us; speedup 1.0000x reference)
//
#include <hip/hip_runtime.h>

// 2-layer GCN: h1 = emb[x] @ W1; agg+b1+relu; @ W2; agg+b2.
// Graph aggregation via CSR built per-launch (counting sort by dst).

#define BS 256

__global__ void k_deg(const int* __restrict__ dst, int E, int* __restrict__ deg) {
    int i = blockIdx.x * blockDim.x + threadIdx.x;
    if (i < E) atomicAdd(&deg[dst[i]], 1);
}

// exclusive scan within blocks of 256; emit per-block totals
__global__ void k_scanA(const int* __restrict__ deg, int N,
                        int* __restrict__ partial, int* __restrict__ bsum) {
    __shared__ int s[BS];
    int t = threadIdx.x;
    int i = blockIdx.x * BS + t;
    int v = (i < N) ? deg[i] : 0;
    s[t] = v;
    __syncthreads();
    for (int off = 1; off < BS; off <<= 1) {
        int add = (t >= off) ? s[t - off] : 0;
        __syncthreads();
        s[t] += add;
        __syncthreads();
    }
    if (i < N) partial[i] = s[t] - v;          // exclusive
    if (t == BS - 1) bsum[blockIdx.x] = s[BS - 1];
}

// serial scan of block sums (nB ~ 391, trivial)
__global__ void k_scanB(const int* __restrict__ bsum, int nB, int* __restrict__ boff) {
    if (threadIdx.x == 0 && blockIdx.x == 0) {
        int acc = 0;
        for (int b = 0; b < nB; b++) { boff[b] = acc; acc += bsum[b]; }
    }
}

// finalize row_start, cursor copy, dinv = rsqrt(deg_edges + 1 self-loop)
__global__ void k_scanC(const int* __restrict__ deg, const int* __restrict__ partial,
                        const int* __restrict__ boff, int N,
                        int* __restrict__ row_start, int* __restrict__ cursor,
                        float* __restrict__ dinv) {
    int i = blockIdx.x * blockDim.x + threadIdx.x;
    if (i < N) {
        int rs = partial[i] + boff[i >> 8];
        row_start[i] = rs;
        cursor[i] = rs;
        dinv[i] = rsqrtf((float)(deg[i] + 1));
    }
}

__global__ void k_scatter(const int* __restrict__ src, const int* __restrict__ dst, int E,
                          int* __restrict__ cursor, int* __restrict__ col) {
    int i = blockIdx.x * blockDim.x + threadIdx.x;
    if (i < E) {
        int d = dst[i];
        int pos = atomicAdd(&cursor[d], 1);
        col[pos] = src[i];
    }
}

// h1[n][c] = sum_k emb[x[n]][k] * W1[k][c]   (N x 16 @ 16 x 32)
// block = 256 threads = 8 nodes x 32 channels
__global__ void k_mm1(const int* __restrict__ x, const float* __restrict__ emb,
                      const float* __restrict__ W1, int N, float* __restrict__ h1) {
    __shared__ float sW[16 * 32];
    __shared__ float sE[8][17];                 // +1 pad
    int t = threadIdx.x;
    sW[t] = W1[t];
    sW[t + 256] = W1[t + 256];
    int n0 = blockIdx.x * 8;
    if (t < 128) {
        int nl = t >> 4, k = t & 15;
        int n = n0 + nl;
        sE[nl][k] = (n < N) ? emb[x[n] * 16 + k] : 0.f;
    }
    __syncthreads();
    int nl = t >> 5, c = t & 31;
    int n = n0 + nl;
    if (n < N) {
        float acc = 0.f;
        #pragma unroll
        for (int k = 0; k < 16; k++) acc += sE[nl][k] * sW[k * 32 + c];
        h1[n * 32 + c] = acc;
    }
}

// fused: layer-1 aggregate (+b1, relu) -> LDS -> GEMM with W2 -> h2
// block = 256 = 8 nodes x 32 channels (agg phase); 128 threads for mm phase
__global__ void k_agg1mm2(const float* __restrict__ h1, const int* __restrict__ row_start,
                          const int* __restrict__ deg, const float* __restrict__ dinv,
                          const int* __restrict__ col, const float* __restrict__ b1,
                          const float* __restrict__ W2, int N, float* __restrict__ h2) {
    __shared__ float sH[8][33];                 // +1 pad breaks 4-way conflict in mm phase
    __shared__ float sW[32 * 16];
    int t = threadIdx.x;
    sW[t] = W2[t];
    sW[t + 256] = W2[t + 256];
    int nl = t >> 5, c = t & 31;
    int n = blockIdx.x * 8 + nl;
    float val = 0.f;
    if (n < N) {
        int rs = row_start[n];
        int dn = deg[n];
        float acc = 0.f;
        for (int e = 0; e < dn; e++) {
            int s = col[rs + e];                // broadcast across 32 lanes
            acc += dinv[s] * h1[s * 32 + c];    // coalesced 128B gather
        }
        float di = dinv[n];
        acc += di * h1[n * 32 + c];             // self-loop
        val = fmaxf(acc * di + b1[c], 0.f);     // norm factor + bias + relu
    }
    sH[nl][c] = val;
    __syncthreads();
    if (t < 128) {
        int nl2 = t >> 4, co = t & 15;
        int n2 = blockIdx.x * 8 + nl2;
        if (n2 < N) {
            float acc = 0.f;
            #pragma unroll
            for (int k = 0; k < 32; k++) acc += sH[nl2][k] * sW[k * 16 + co];
            h2[n2 * 16 + co] = acc;             // b2 applied after aggregation
        }
    }
}

// layer-2 aggregate + b2 -> out.  block = 256 = 16 nodes x 16 channels
__global__ void k_agg2(const float* __restrict__ h2, const int* __restrict__ row_start,
                       const int* __restrict__ deg, const float* __restrict__ dinv,
                       const int* __restrict__ col, const float* __restrict__ b2,
                       int N, float* __restrict__ out) {
    int t = threadIdx.x;
    int nl = t >> 4, c = t & 15;
    int n = blockIdx.x * 16 + nl;
    if (n >= N) return;
    int rs = row_start[n];
    int dn = deg[n];
    float acc = 0.f;
    for (int e = 0; e < dn; e++) {
        int s = col[rs + e];
        acc += dinv[s] * h2[s * 16 + c];        // coalesced 64B gather
    }
    float di = dinv[n];
    acc += di * h2[n * 16 + c];
    out[n * 16 + c] = acc * di + b2[c];
}

extern "C" void kernel_launch(void* const* d_in, const int* in_sizes, int n_in,
                              void* d_out, int out_size, void* d_ws, size_t ws_size,
                              hipStream_t stream) {
    const int*   x   = (const int*)d_in[0];
    const int*   ei  = (const int*)d_in[1];
    const float* emb = (const float*)d_in[2];
    const float* W1  = (const float*)d_in[3];
    const float* b1  = (const float*)d_in[4];
    const float* W2  = (const float*)d_in[5];
    const float* b2  = (const float*)d_in[6];
    float* out = (float*)d_out;

    const int N = in_sizes[0];
    const int E = in_sizes[1] / 2;
    const int* srcp = ei;
    const int* dstp = ei + E;
    const int nB = (N + BS - 1) / BS;

    // workspace carve (256B aligned)
    char* w = (char*)d_ws;
    auto carve = [&](size_t bytes) {
        void* p = (void*)w;
        w += (bytes + 255) & ~size_t(255);
        return p;
    };
    int*   deg       = (int*)carve((size_t)N * 4);
    int*   partial   = (int*)carve((size_t)N * 4);
    int*   bsum      = (int*)carve((size_t)nB * 4);
    int*   boff      = (int*)carve((size_t)nB * 4);
    int*   row_start = (int*)carve((size_t)N * 4);
    int*   cursor    = (int*)carve((size_t)N * 4);
    float* dinv      = (float*)carve((size_t)N * 4);
    int*   col       = (int*)carve((size_t)E * 4);
    float* h1        = (float*)carve((size_t)N * 32 * 4);
    float* h2        = (float*)carve((size_t)N * 16 * 4);
    (void)ws_size; (void)n_in; (void)out_size;

    hipMemsetAsync(deg, 0, (size_t)N * 4, stream);

    int gE = (E + BS - 1) / BS;
    int gN = (N + BS - 1) / BS;
    k_deg<<<gE, BS, 0, stream>>>(dstp, E, deg);
    k_scanA<<<gN, BS, 0, stream>>>(deg, N, partial, bsum);
    k_scanB<<<1, 64, 0, stream>>>(bsum, nB, boff);
    k_scanC<<<gN, BS, 0, stream>>>(deg, partial, boff, N, row_start, cursor, dinv);
    k_scatter<<<gE, BS, 0, stream>>>(srcp, dstp, E, cursor, col);

    int g8  = (N + 7) / 8;     // 8 nodes/block
    int g16 = (N + 15) / 16;   // 16 nodes/block
    k_mm1<<<g8, BS, 0, stream>>>(x, emb, W1, N, h1);
    k_agg1mm2<<<g8, BS, 0, stream>>>(h1, row_start, deg, dinv, col, b1, W2, N, h2);
    k_agg2<<<g16, BS, 0, stream>>>(h2, row_start, deg, dinv, col, b2, N, out);
}

// Round 2
// 289.167 us; speedup vs baseline: 1.5429x; 1.5429x over previous
//
#include <hip/hip_runtime.h>

// 2-layer GCN: h1 = emb[x] @ W1; agg+b1+relu; @ W2; agg+b2.
// CSR built per-launch via two-level binned counting sort (NO global atomics:
// R1 showed 1.6M device-scope atomics cost ~64B memory-side traffic each).

#define BS   256
#define NBLK 256          // blocks for hist/binscatter passes
#define BINSHIFT 7        // 128 nodes per bin
#define MAXBINS 1024

// ---- pass A: per-block histograms of dst bins -------------------------------
__global__ void k_hist(const int* __restrict__ dst, int E, int NBINS,
                       int* __restrict__ histG) {
    __shared__ int h[MAXBINS];
    int t = threadIdx.x;
    for (int i = t; i < NBINS; i += BS) h[i] = 0;
    __syncthreads();
    int chunk = (E + NBLK - 1) / NBLK;
    int s = blockIdx.x * chunk;
    int eend = s + chunk; if (eend > E) eend = E;
    for (int e = s + t; e < eend; e += BS) atomicAdd(&h[dst[e] >> BINSHIFT], 1);
    __syncthreads();
    // bin-major layout: histG[bin*NBLK + blk] so a flat scan yields offsets
    for (int i = t; i < NBINS; i += BS) histG[i * NBLK + blockIdx.x] = h[i];
}

// ---- hierarchical exclusive scan over L = NBINS*NBLK ints -------------------
__global__ void k_scanA(const int* __restrict__ in, int L,
                        int* __restrict__ partial, int* __restrict__ bsum) {
    __shared__ int s[BS];
    int t = threadIdx.x;
    int i = blockIdx.x * BS + t;
    int v = (i < L) ? in[i] : 0;
    s[t] = v;
    __syncthreads();
    for (int off = 1; off < BS; off <<= 1) {
        int add = (t >= off) ? s[t - off] : 0;
        __syncthreads();
        s[t] += add;
        __syncthreads();
    }
    if (i < L) partial[i] = s[t] - v;          // exclusive within block
    if (t == BS - 1) bsum[blockIdx.x] = s[BS - 1];
}

// parallel single-block scan of block sums (R1's serial loop was latency-bound)
__global__ void k_scanB(const int* __restrict__ bsum, int nB, int* __restrict__ boff) {
    __shared__ int s[BS];
    int t = threadIdx.x;
    int PER = (nB + BS - 1) / BS;              // <=8 for nB<=2048
    int loc[8];
    int base = t * PER;
    int sum = 0;
    for (int j = 0; j < PER && j < 8; j++) {
        int idx = base + j;
        int v = (idx < nB) ? bsum[idx] : 0;
        loc[j] = sum;
        sum += v;
    }
    s[t] = sum;
    __syncthreads();
    for (int off = 1; off < BS; off <<= 1) {
        int add = (t >= off) ? s[t - off] : 0;
        __syncthreads();
        s[t] += add;
        __syncthreads();
    }
    int ex = s[t] - sum;
    for (int j = 0; j < PER && j < 8; j++) {
        int idx = base + j;
        if (idx < nB) boff[idx] = ex + loc[j];
    }
}

__global__ void k_scanC(const int* __restrict__ partial, const int* __restrict__ boff,
                        int L, int* __restrict__ outArr) {
    int i = blockIdx.x * BS + threadIdx.x;
    if (i < L) outArr[i] = partial[i] + boff[i >> 8];
}

// ---- pass C: scatter edges into bin-partitioned order (LDS cursors only) ----
__global__ void k_binscatter(const int* __restrict__ src, const int* __restrict__ dst,
                             int E, int NBINS, const int* __restrict__ scanArr,
                             int2* __restrict__ pairs) {
    __shared__ int cur[MAXBINS];
    int t = threadIdx.x;
    for (int i = t; i < NBINS; i += BS) cur[i] = scanArr[i * NBLK + blockIdx.x];
    __syncthreads();
    int chunk = (E + NBLK - 1) / NBLK;
    int s = blockIdx.x * chunk;
    int eend = s + chunk; if (eend > E) eend = E;
    for (int e = s + t; e < eend; e += BS) {
        int d = dst[e];
        int pos = atomicAdd(&cur[d >> BINSHIFT], 1);     // LDS atomic
        pairs[pos] = make_int2(src[e], d);               // 8B store, line-local runs
    }
}

// ---- pass D: per-bin counting sort -> final CSR + deg/row_start/dinv --------
__global__ void k_binsort(const int2* __restrict__ pairs, const int* __restrict__ scanArr,
                          int NBINS, int N, int E,
                          int* __restrict__ row_start, int* __restrict__ deg,
                          float* __restrict__ dinv, int* __restrict__ col) {
    __shared__ int ldeg[128];
    __shared__ int lrs[128];
    __shared__ int cur[128];
    int b = blockIdx.x;
    int t = threadIdx.x;
    int node0 = b << BINSHIFT;
    int e0 = scanArr[b * NBLK];
    int e1 = (b + 1 < NBINS) ? scanArr[(b + 1) * NBLK] : E;
    if (t < 128) ldeg[t] = 0;
    __syncthreads();
    for (int e = e0 + t; e < e1; e += BS)
        atomicAdd(&ldeg[pairs[e].y - node0], 1);
    __syncthreads();
    if (t < 128) lrs[t] = ldeg[t];
    __syncthreads();
    for (int off = 1; off < 128; off <<= 1) {
        int add = (t < 128 && t >= off) ? lrs[t - off] : 0;
        __syncthreads();
        if (t < 128) lrs[t] += add;
        __syncthreads();
    }
    if (t < 128) {
        int ex = lrs[t] - ldeg[t];               // exclusive
        cur[t] = ex;
        int n = node0 + t;
        if (n < N) {
            row_start[n] = e0 + ex;
            deg[n] = ldeg[t];
            dinv[n] = rsqrtf((float)(ldeg[t] + 1));
        }
    }
    __syncthreads();
    for (int e = e0 + t; e < e1; e += BS) {
        int2 p = pairs[e];
        int pos = atomicAdd(&cur[p.y - node0], 1);       // LDS atomic
        col[e0 + pos] = p.x;                             // write within bin range
    }
}

// ---- h1[n][c] = sum_k emb[x[n]][k] * W1[k][c]   (N x 16 @ 16 x 32) ----------
__global__ void k_mm1(const int* __restrict__ x, const float* __restrict__ emb,
                      const float* __restrict__ W1, int N, float* __restrict__ h1) {
    __shared__ float sW[16 * 32];
    __shared__ float sE[8][17];
    int t = threadIdx.x;
    sW[t] = W1[t];
    sW[t + 256] = W1[t + 256];
    int n0 = blockIdx.x * 8;
    if (t < 128) {
        int nl = t >> 4, k = t & 15;
        int n = n0 + nl;
        sE[nl][k] = (n < N) ? emb[x[n] * 16 + k] : 0.f;
    }
    __syncthreads();
    int nl = t >> 5, c = t & 31;
    int n = n0 + nl;
    if (n < N) {
        float acc = 0.f;
        #pragma unroll
        for (int k = 0; k < 16; k++) acc += sE[nl][k] * sW[k * 32 + c];
        h1[n * 32 + c] = acc;
    }
}

// ---- fused: layer-1 aggregate (+b1, relu) -> LDS -> GEMM W2 -> h2 -----------
__global__ void k_agg1mm2(const float* __restrict__ h1, const int* __restrict__ row_start,
                          const int* __restrict__ deg, const float* __restrict__ dinv,
                          const int* __restrict__ col, const float* __restrict__ b1,
                          const float* __restrict__ W2, int N, float* __restrict__ h2) {
    __shared__ float sH[8][33];
    __shared__ float sW[32 * 16];
    int t = threadIdx.x;
    sW[t] = W2[t];
    sW[t + 256] = W2[t + 256];
    int nl = t >> 5, c = t & 31;
    int n = blockIdx.x * 8 + nl;
    float val = 0.f;
    if (n < N) {
        int rs = row_start[n];
        int dn = deg[n];
        float acc = 0.f;
        for (int e = 0; e < dn; e++) {
            int s = col[rs + e];
            acc += dinv[s] * h1[s * 32 + c];
        }
        float di = dinv[n];
        acc += di * h1[n * 32 + c];
        val = fmaxf(acc * di + b1[c], 0.f);
    }
    sH[nl][c] = val;
    __syncthreads();
    if (t < 128) {
        int nl2 = t >> 4, co = t & 15;
        int n2 = blockIdx.x * 8 + nl2;
        if (n2 < N) {
            float acc = 0.f;
            #pragma unroll
            for (int k = 0; k < 32; k++) acc += sH[nl2][k] * sW[k * 16 + co];
            h2[n2 * 16 + co] = acc;
        }
    }
}

// ---- layer-2 aggregate + b2 -> out ------------------------------------------
__global__ void k_agg2(const float* __restrict__ h2, const int* __restrict__ row_start,
                       const int* __restrict__ deg, const float* __restrict__ dinv,
                       const int* __restrict__ col, const float* __restrict__ b2,
                       int N, float* __restrict__ out) {
    int t = threadIdx.x;
    int nl = t >> 4, c = t & 15;
    int n = blockIdx.x * 16 + nl;
    if (n >= N) return;
    int rs = row_start[n];
    int dn = deg[n];
    float acc = 0.f;
    for (int e = 0; e < dn; e++) {
        int s = col[rs + e];
        acc += dinv[s] * h2[s * 16 + c];
    }
    float di = dinv[n];
    acc += di * h2[n * 16 + c];
    out[n * 16 + c] = acc * di + b2[c];
}

extern "C" void kernel_launch(void* const* d_in, const int* in_sizes, int n_in,
                              void* d_out, int out_size, void* d_ws, size_t ws_size,
                              hipStream_t stream) {
    const int*   x   = (const int*)d_in[0];
    const int*   ei  = (const int*)d_in[1];
    const float* emb = (const float*)d_in[2];
    const float* W1  = (const float*)d_in[3];
    const float* b1  = (const float*)d_in[4];
    const float* W2  = (const float*)d_in[5];
    const float* b2  = (const float*)d_in[6];
    float* out = (float*)d_out;

    const int N = in_sizes[0];
    const int E = in_sizes[1] / 2;
    const int* srcp = ei;
    const int* dstp = ei + E;
    const int NBINS = (N + 127) >> BINSHIFT;   // 782 for N=100000
    const int L = NBINS * NBLK;                // scan length
    const int nB2 = (L + BS - 1) / BS;

    char* w = (char*)d_ws;
    auto carve = [&](size_t bytes) {
        void* p = (void*)w;
        w += (bytes + 255) & ~size_t(255);
        return p;
    };
    int*   histG     = (int*)carve((size_t)L * 4);
    int*   partial   = (int*)carve((size_t)L * 4);
    int*   bsum      = (int*)carve((size_t)nB2 * 4);
    int*   boff      = (int*)carve((size_t)nB2 * 4);
    int*   scanArr   = (int*)carve((size_t)L * 4);
    int*   row_start = (int*)carve((size_t)N * 4);
    int*   deg       = (int*)carve((size_t)N * 4);
    float* dinv      = (float*)carve((size_t)N * 4);
    int*   col       = (int*)carve((size_t)E * 4);
    // pairs (int2, E*8) and h1 (N*32*4) have disjoint lifetimes -> share
    size_t pairsB = (size_t)E * 8, h1B = (size_t)N * 32 * 4;
    void*  shared12  = carve(pairsB > h1B ? pairsB : h1B);
    int2*  pairs     = (int2*)shared12;
    float* h1        = (float*)shared12;
    float* h2        = (float*)carve((size_t)N * 16 * 4);
    (void)ws_size; (void)n_in; (void)out_size;

    int gL = (L + BS - 1) / BS;
    k_hist<<<NBLK, BS, 0, stream>>>(dstp, E, NBINS, histG);
    k_scanA<<<gL, BS, 0, stream>>>(histG, L, partial, bsum);
    k_scanB<<<1, BS, 0, stream>>>(bsum, nB2, boff);
    k_scanC<<<gL, BS, 0, stream>>>(partial, boff, L, scanArr);
    k_binscatter<<<NBLK, BS, 0, stream>>>(srcp, dstp, E, NBINS, scanArr, pairs);
    k_binsort<<<NBINS, BS, 0, stream>>>(pairs, scanArr, NBINS, N, E,
                                        row_start, deg, dinv, col);

    int g8  = (N + 7) / 8;
    int g16 = (N + 15) / 16;
    k_mm1<<<g8, BS, 0, stream>>>(x, emb, W1, N, h1);
    k_agg1mm2<<<g8, BS, 0, stream>>>(h1, row_start, deg, dinv, col, b1, W2, N, h2);
    k_agg2<<<g16, BS, 0, stream>>>(h2, row_start, deg, dinv, col, b2, N, out);
}